// Round 5
// baseline (122.681 us; speedup 1.0000x reference)
//
#include <hip/hip_runtime.h>
#include <math.h>

#define PI_F 3.14159265358979323846f

typedef __attribute__((ext_vector_type(8))) short bf16x8;   // 8 bf16 (4 VGPRs)
typedef __attribute__((ext_vector_type(4))) float f32x4;    // MFMA C/D

// Persistent device tables (rewritten fully on every launch).
__device__ float g_sang[48];       // style angles [b][q] (tanh*pi applied)
__device__ float g_cb[64];         // out_proj_b + res_proj_b
__device__ __attribute__((aligned(16))) unsigned short g_Urb[64 * 64];  // [t][s]
__device__ __attribute__((aligned(16))) unsigned short g_Uib[64 * 64];  // [t][s]
__device__ __attribute__((aligned(16))) unsigned short g_Zwc[64 * 64];  // [c][t]
// MFMA B operand for conv GEMM: [ntile(5)][slab(18)][lane(64)][j(8)]
__device__ __attribute__((aligned(16))) unsigned short g_Bm[5 * 18 * 64 * 8];

__device__ inline unsigned short bf16rne(float f) {
    unsigned u = __float_as_uint(f);
    return (unsigned short)((u + 0x7FFFu + ((u >> 16) & 1u)) >> 16);
}
__device__ inline float rlane(float v, int k) {
    return __uint_as_float(__builtin_amdgcn_readlane(__float_as_uint(v), k));
}

// ---------------------------------------------------------------------------
// k_prep: 8 blocks x 1024 threads (verbatim R4, proven).
//   bid 0   : circuit columns (16 waves x 4 cols, lane-parallel trig)
//   bid 1..6: Bm build (5760 fragment entries, 16 B store each)
//   bid 7   : Zw (transposed bf16) + combined bias + style angles
__global__ __launch_bounds__(1024) void k_prep(
        const float* __restrict__ style,
        const float* __restrict__ dw, const float* __restrict__ rw,
        const float* __restrict__ s2dw, const float* __restrict__ s2db,
        const float* __restrict__ qcnn, const float* __restrict__ meas,
        const float* __restrict__ outw, const float* __restrict__ outb,
        const float* __restrict__ resb) {
    int bid  = blockIdx.x;
    int tid  = threadIdx.x;
    int lane = tid & 63;
    int wid  = tid >> 6;

    if (bid >= 1 && bid <= 6) {   // Bm build
        int entry = (bid - 1) * 1024 + tid;
        if (entry < 5760) {
            int nt   = entry / 1152;
            int rem  = entry - nt * 1152;
            int slab = rem >> 6;
            int ln   = rem & 63;
            int mm   = ln & 15, qq = ln >> 4;
            int n    = nt * 16 + mm;
            int ij   = slab >> 1;
            int ch   = (slab & 1) * 32 + qq * 8;
            unsigned pk[4] = {0u, 0u, 0u, 0u};
            if (n < 70) {
                const float* src = (n < 64) ? (rw + n * 576 + ij)
                                            : (dw + (n - 64) * 576 + ij);
#pragma unroll
                for (int jj = 0; jj < 4; ++jj) {
                    pk[jj] = (unsigned)bf16rne(src[(ch + 2 * jj) * 9])
                           | ((unsigned)bf16rne(src[(ch + 2 * jj + 1) * 9]) << 16);
                }
            }
            *(uint4*)(g_Bm + entry * 8) = make_uint4(pk[0], pk[1], pk[2], pk[3]);
        }
        return;
    }

    if (bid == 7) {   // Zw + cb + sang
        float zr[6];
#pragma unroll
        for (int q = 0; q < 6; ++q) zr[q] = ((lane >> (5 - q)) & 1) ? -1.f : 1.f;
#pragma unroll
        for (int cc = 0; cc < 4; ++cc) {
            int c = wid * 4 + cc;
            float z = 0.f;
#pragma unroll
            for (int q = 0; q < 6; ++q) z += outw[c * 6 + q] * zr[q];
            g_Zwc[c * 64 + lane] = bf16rne(z);
        }
        if (wid == 0) g_cb[lane] = outb[lane] + resb[lane];
        if (wid == 1 && lane < 48) {
            int bb = lane / 6, q = lane % 6;
            float a = s2db[q];
#pragma unroll 8
            for (int j = 0; j < 128; ++j) a += style[bb * 128 + j] * s2dw[q * 128 + j];
            g_sang[lane] = tanhf(a) * PI_F;
        }
        return;
    }

    // ---- bid 0: circuit. Lane-parallel trig table, then 4 columns per wave.
    float tsv, tcv;
    {
        int idx = lane < 48 ? lane : 0;
        float arg;
        if (idx < 24) {
            arg = 0.5f * qcnn[idx * 3];
        } else {
            int q3 = (idx - 24) >> 2, part = (idx - 24) & 3;
            float th = meas[q3 * 3 + 0], ph = meas[q3 * 3 + 1], lm = meas[q3 * 3 + 2];
            arg = part == 0 ? 0.5f * th : part == 1 ? lm : part == 2 ? ph : ph + lm;
        }
        sincosf(arg, &tsv, &tcv);
    }
    int s0 = wid * 4;
    float ar[4], ai[4];
#pragma unroll
    for (int cc = 0; cc < 4; ++cc) {
        ar[cc] = (lane == s0 + cc) ? 1.f : 0.f;
        ai[cc] = 0.f;
    }
#pragma unroll
    for (int l = 0; l < 2; ++l) {
#pragma unroll
        for (int wq = 0; wq < 6; ++wq) {
            int mask = 1 << (5 - wq);
            bool hi = (lane & mask) != 0;
            int g = (l * 6 + wq) * 2;
            float sg = rlane(tsv, g),     cg = rlane(tcv, g);
            float sz = rlane(tsv, g + 1), cz = rlane(tcv, g + 1);
            float szz = hi ? sz : -sz;
#pragma unroll
            for (int cc = 0; cc < 4; ++cc) {
                float pr  = __shfl_xor(ar[cc], mask);
                float pi2 = __shfl_xor(ai[cc], mask);
                float nr = hi ? (sg * pr + cg * ar[cc]) : (cg * ar[cc] - sg * pr);
                float ni = hi ? (sg * pi2 + cg * ai[cc]) : (cg * ai[cc] - sg * pi2);
                ar[cc] = cz * nr - szz * ni;
                ai[cc] = cz * ni + szz * nr;
            }
        }
#pragma unroll
        for (int wq = 0; wq < 6; ++wq) {  // ring CNOTs
            int cm = 1 << (5 - wq);
            int tm = 1 << (5 - ((wq + 1) % 6));
#pragma unroll
            for (int cc = 0; cc < 4; ++cc) {
                float pr  = __shfl_xor(ar[cc], tm);
                float pi2 = __shfl_xor(ai[cc], tm);
                if (lane & cm) { ar[cc] = pr; ai[cc] = pi2; }
            }
        }
    }
#pragma unroll
    for (int wq = 0; wq < 6; ++wq) {  // U3 measurement basis
        int mask = 1 << (5 - wq);
        bool hi = (lane & mask) != 0;
        int u = 24 + wq * 4;
        float st2 = rlane(tsv, u),     ct  = rlane(tcv, u);
        float sl  = rlane(tsv, u + 1), cl  = rlane(tcv, u + 1);
        float sp  = rlane(tsv, u + 2), cp  = rlane(tcv, u + 2);
        float spl = rlane(tsv, u + 3), cpl = rlane(tcv, u + 3);
        float u01r = -cl * st2, u01i = -sl * st2;
        float u10r =  cp * st2, u10i =  sp * st2;
        float u11r =  cpl * ct, u11i =  spl * ct;
#pragma unroll
        for (int cc = 0; cc < 4; ++cc) {
            float pr  = __shfl_xor(ar[cc], mask);
            float pi2 = __shfl_xor(ai[cc], mask);
            float nr, ni;
            if (hi) {
                nr = u10r * pr - u10i * pi2 + u11r * ar[cc] - u11i * ai[cc];
                ni = u10r * pi2 + u10i * pr + u11r * ai[cc] + u11i * ar[cc];
            } else {
                nr = ct * ar[cc] + u01r * pr - u01i * pi2;
                ni = ct * ai[cc] + u01r * pi2 + u01i * pr;
            }
            ar[cc] = nr; ai[cc] = ni;
        }
    }
    unsigned short rr[4], ii[4];
#pragma unroll
    for (int cc = 0; cc < 4; ++cc) { rr[cc] = bf16rne(ar[cc]); ii[cc] = bf16rne(ai[cc]); }
    *(uint2*)(g_Urb + lane * 64 + s0) =
        make_uint2((unsigned)rr[0] | ((unsigned)rr[1] << 16),
                   (unsigned)rr[2] | ((unsigned)rr[3] << 16));
    *(uint2*)(g_Uib + lane * 64 + s0) =
        make_uint2((unsigned)ii[0] | ((unsigned)ii[1] << 16),
                   (unsigned)ii[2] | ((unsigned)ii[3] << 16));
}

// ---------------------------------------------------------------------------
// k_main: 512 blocks x 512 threads (8 waves) = 64 pixels x 4 blocks/CU.
// xs padded to 37 dwords/row (conflict-free staging writes).
// Each wave owns TWO output tiles (mtA, nt0) and (mtA+2, nt0) sharing B-frags;
// conv acc stays in registers through the epilogue (register fusion).
// LDS (floats): [0,7326) xs bf16 [3][66][74ush]; overlays after conv:
//   fact [0,768), psi_bf [1024,3328), p_bf [3328,5632); angs [7326,7838).
__global__ __launch_bounds__(512, 8) void k_main(const float* __restrict__ x,
                                                 const float* __restrict__ dpb,
                                                 float* __restrict__ out) {
    __shared__ __attribute__((aligned(16))) float smem[7838];   // 31352 B
    unsigned*             xsu32 = (unsigned*)smem;
    const unsigned short* xsu   = (const unsigned short*)smem;
    float*          fact    = smem;                             // [12][64]
    unsigned short* psi_bf  = (unsigned short*)(smem + 1024);   // [64][72]
    unsigned short* p_bf    = (unsigned short*)(smem + 3328);   // [64][72]
    float*          angs    = smem + 7326;                      // [64][8]

    int tid  = threadIdx.x;
    int lane = tid & 63;                 // pixel within block (== w)
    int wid  = __builtin_amdgcn_readfirstlane(tid >> 6);  // 0..7
    int m    = lane & 15;
    int quad = lane >> 4;

    int p = blockIdx.x * 64 + lane;      // pixel id: b*4096 + h*64 + w
    int b = p >> 12;                     // block-uniform
    int h = (p >> 6) & 63;               // block-uniform
    const float* xb = x + (b << 18);

    // ---- stage x-tile as bf16 (stride-37 rows: conflict-free writes)
    if (tid < 222) {  // zero halo: 3 rows x 2 cols x 37 uints
        int r3 = tid / 74, rest = tid % 74;
        int half = rest / 37, cp = rest % 37;
        xsu32[(r3 * 66 + half * 65) * 37 + cp] = 0u;
    }
#pragma unroll
    for (int k = 0; k < 12; ++k) {
        int flat = k * 512 + tid;        // 0..6143 = 3 rows x 32 cpairs x 64 w
        int row  = flat >> 11;
        int rem  = flat & 2047;
        int cp   = rem >> 6;
        int w2   = rem & 63;
        int hh   = h + row - 1;
        float v0 = 0.f, v1 = 0.f;
        if ((unsigned)hh < 64u) {
            const float* px = xb + (hh << 6) + w2;
            v0 = px[(2 * cp) << 12];
            v1 = px[(2 * cp + 1) << 12];
        }
        xsu32[(row * 66 + w2 + 1) * 37 + cp] =
            (unsigned)bf16rne(v0) | ((unsigned)bf16rne(v1) << 16);
    }
    __syncthreads();   // B1

    // ---- conv+angle MFMA GEMM (A: LDS stride-74, B: g_Bm global/L2)
    int mtA = wid >> 2;                  // 0..1; wave owns mtA and mtA+2
    int nt0 = wid & 3;
    const unsigned short* aAbase = xsu + (mtA * 16 + m) * 74 + quad * 8;
    const unsigned short* aBbase = xsu + ((mtA + 2) * 16 + m) * 74 + quad * 8;
    const unsigned short* b0base = g_Bm + ((nt0 * 18) * 64 + lane) * 8;
    f32x4 acc0a = {0.f, 0.f, 0.f, 0.f};
    f32x4 acc0b = {0.f, 0.f, 0.f, 0.f};
    f32x4 acc1  = {0.f, 0.f, 0.f, 0.f};
    if (wid < 4) {
        const unsigned short* a1base = xsu + (wid * 16 + m) * 74 + quad * 8;
        const unsigned short* b1base = g_Bm + ((4 * 18) * 64 + lane) * 8;
#pragma unroll
        for (int slab = 0; slab < 18; ++slab) {
            int ij = slab >> 1, i = ij / 3, j = ij - 3 * (ij / 3);
            int aoff = i * 4884 + j * 74 + (slab & 1) * 32;
            bf16x8 b0 = *(const bf16x8*)(b0base + slab * 512);
            bf16x8 aA = *(const bf16x8*)(aAbase + aoff);
            acc0a = __builtin_amdgcn_mfma_f32_16x16x32_bf16(aA, b0, acc0a, 0, 0, 0);
            bf16x8 aB = *(const bf16x8*)(aBbase + aoff);
            acc0b = __builtin_amdgcn_mfma_f32_16x16x32_bf16(aB, b0, acc0b, 0, 0, 0);
            bf16x8 a1 = *(const bf16x8*)(a1base + aoff);
            bf16x8 b1 = *(const bf16x8*)(b1base + slab * 512);
            acc1 = __builtin_amdgcn_mfma_f32_16x16x32_bf16(a1, b1, acc1, 0, 0, 0);
        }
    } else {
#pragma unroll
        for (int slab = 0; slab < 18; ++slab) {
            int ij = slab >> 1, i = ij / 3, j = ij - 3 * (ij / 3);
            int aoff = i * 4884 + j * 74 + (slab & 1) * 32;
            bf16x8 b0 = *(const bf16x8*)(b0base + slab * 512);
            bf16x8 aA = *(const bf16x8*)(aAbase + aoff);
            acc0a = __builtin_amdgcn_mfma_f32_16x16x32_bf16(aA, b0, acc0a, 0, 0, 0);
            bf16x8 aB = *(const bf16x8*)(aBbase + aoff);
            acc0b = __builtin_amdgcn_mfma_f32_16x16x32_bf16(aB, b0, acc0b, 0, 0, 0);
        }
    }
    // angle columns (acc1, m<6) -> angs[pix][q]; angs disjoint from xs.
    if (wid < 4 && m < 6) {
#pragma unroll
        for (int r = 0; r < 4; ++r) {
            angs[(wid * 16 + quad * 4 + r) * 8 + m] = acc1[r];
        }
    }
    __syncthreads();   // B2 (conv done: xs dead, angs visible)

    // ---- factors: waves 0-5 compute sincos(theta_q/2) for all 64 pixels
    if (wid < 6) {
        int q = wid;
        float tv = angs[lane * 8 + q];
        float theta = tanhf(tv + dpb[q]) * PI_F + g_sang[b * 6 + q];
        float sv, cv; sincosf(0.5f * theta, &sv, &cv);
        fact[q * 64 + lane] = sv;
        fact[(6 + q) * 64 + lane] = cv;
    }
    __syncthreads();   // B3

    // ---- psi (bf16): each wave builds states 8*wid..8*wid+7 for its pixel
    {
        float f0s = fact[0 * 64 + lane], f0c = fact[6 * 64 + lane];
        float f1s = fact[1 * 64 + lane], f1c = fact[7 * 64 + lane];
        float f2s = fact[2 * 64 + lane], f2c = fact[8 * 64 + lane];
        float f3s = fact[3 * 64 + lane], f3c = fact[9 * 64 + lane];
        float f4s = fact[4 * 64 + lane], f4c = fact[10 * 64 + lane];
        float f5s = fact[5 * 64 + lane], f5c = fact[11 * 64 + lane];
        int sb = wid * 8;
        float pre = (((sb >> 5) & 1) ? f0s : f0c)
                  * (((sb >> 4) & 1) ? f1s : f1c)
                  * (((sb >> 3) & 1) ? f2s : f2c);
        unsigned short pk[8];
#pragma unroll
        for (int ti = 0; ti < 8; ++ti) {
            float v = pre * ((ti & 4) ? f3s : f3c)
                          * ((ti & 2) ? f4s : f4c)
                          * ((ti & 1) ? f5s : f5c);
            pk[ti] = bf16rne(v);
        }
        *(uint4*)(psi_bf + lane * 72 + sb) =
            make_uint4((unsigned)pk[0] | ((unsigned)pk[1] << 16),
                       (unsigned)pk[2] | ((unsigned)pk[3] << 16),
                       (unsigned)pk[4] | ((unsigned)pk[5] << 16),
                       (unsigned)pk[6] | ((unsigned)pk[7] << 16));
    }
    __syncthreads();   // B4

    // ---- GEMM 1/2: Yr/Yi[pix][t] = psi[pix][s] @ U[t][s]^T  (2 tiles/wave)
    {
        const unsigned short* ur = g_Urb + (nt0 * 16 + m) * 64 + quad * 8;
        const unsigned short* ui = g_Uib + (nt0 * 16 + m) * 64 + quad * 8;
        bf16x8 ur0 = *(const bf16x8*)(ur);
        bf16x8 ur1 = *(const bf16x8*)(ur + 32);
        bf16x8 ui0 = *(const bf16x8*)(ui);
        bf16x8 ui1 = *(const bf16x8*)(ui + 32);
#pragma unroll
        for (int half = 0; half < 2; ++half) {
            int mt = mtA + half * 2;
            const unsigned short* pa = psi_bf + (mt * 16 + m) * 72 + quad * 8;
            bf16x8 aA = *(const bf16x8*)(pa);
            bf16x8 aB = *(const bf16x8*)(pa + 32);
            f32x4 c1 = {0.f, 0.f, 0.f, 0.f};
            f32x4 c2 = {0.f, 0.f, 0.f, 0.f};
            c1 = __builtin_amdgcn_mfma_f32_16x16x32_bf16(aA, ur0, c1, 0, 0, 0);
            c1 = __builtin_amdgcn_mfma_f32_16x16x32_bf16(aB, ur1, c1, 0, 0, 0);
            c2 = __builtin_amdgcn_mfma_f32_16x16x32_bf16(aA, ui0, c2, 0, 0, 0);
            c2 = __builtin_amdgcn_mfma_f32_16x16x32_bf16(aB, ui1, c2, 0, 0, 0);
#pragma unroll
            for (int r = 0; r < 4; ++r) {
                float pv = c1[r] * c1[r] + c2[r] * c2[r];
                p_bf[(mt * 16 + quad * 4 + r) * 72 + nt0 * 16 + m] = bf16rne(pv);
            }
        }
    }
    __syncthreads();   // B5

    // ---- GEMM 3: O[pix][c] = P @ Zw; fuse conv acc + bias, direct store.
    {
        const unsigned short* zc = g_Zwc + (nt0 * 16 + m) * 64 + quad * 8;
        bf16x8 zc0 = *(const bf16x8*)(zc);
        bf16x8 zc1 = *(const bf16x8*)(zc + 32);
        int cch = nt0 * 16 + m;
        float cbv = g_cb[cch];
#pragma unroll
        for (int half = 0; half < 2; ++half) {
            int mt = mtA + half * 2;
            const unsigned short* pa = p_bf + (mt * 16 + m) * 72 + quad * 8;
            f32x4 o = {0.f, 0.f, 0.f, 0.f};
            o = __builtin_amdgcn_mfma_f32_16x16x32_bf16(*(const bf16x8*)(pa), zc0, o, 0, 0, 0);
            o = __builtin_amdgcn_mfma_f32_16x16x32_bf16(*(const bf16x8*)(pa + 32), zc1, o, 0, 0, 0);
            f32x4 acc = half ? acc0b : acc0a;
            float4 res;
            res.x = (acc[0] + o[0]) + cbv;
            res.y = (acc[1] + o[1]) + cbv;
            res.z = (acc[2] + o[2]) + cbv;
            res.w = (acc[3] + o[3]) + cbv;
            int base = (b << 18) + (cch << 12) + (h << 6) + mt * 16 + quad * 4;
            *(float4*)(out + base) = res;
        }
    }
}

// ---------------------------------------------------------------------------
extern "C" void kernel_launch(void* const* d_in, const int* in_sizes, int n_in,
                              void* d_out, int out_size, void* d_ws, size_t ws_size,
                              hipStream_t stream) {
    const float* x     = (const float*)d_in[0];
    const float* style = (const float*)d_in[1];
    const float* dw    = (const float*)d_in[2];
    const float* dpb   = (const float*)d_in[3];
    const float* s2dw  = (const float*)d_in[4];
    const float* s2db  = (const float*)d_in[5];
    const float* qcnn  = (const float*)d_in[6];
    const float* meas  = (const float*)d_in[7];
    const float* outw  = (const float*)d_in[8];
    const float* outb  = (const float*)d_in[9];
    const float* rw    = (const float*)d_in[10];
    const float* resb  = (const float*)d_in[11];
    float* out = (float*)d_out;

    hipLaunchKernelGGL(k_prep, dim3(8), dim3(1024), 0, stream,
                       style, dw, rw, s2dw, s2db, qcnn, meas, outw, outb, resb);
    hipLaunchKernelGGL(k_main, dim3(512), dim3(512), 0, stream, x, dpb, out);
}